// Round 17
// baseline (51.706 us; speedup 1.0000x reference)
//
#include <hip/hip_runtime.h>
#include <hip/hip_fp16.h>
#include <math.h>
#include <stdint.h>

#define LOG2E  1.44269504088896340736f
#define LN2    0.69314718055994530942f
#define LOG2PI 1.8378770664093453f

#define NN 2048
#define DD 64

// f32 Schraudolph (validated r8-r16): scale 2^16, window [2^23,2^24)
#define BIAS_F   16252928.0f
#define KBIT     2205910303u
#define CLAMP_LO 8388608.0f
#define CLAMP_HI 16777215.0f

// f16 Schraudolph (validated r15/r16): y = 32*(arg+7)+1728 in [1250,2048)
#define C1250H 0x64E264E2u
#define KK16   0x63DC63DCu
#define SHL5   0x00050005u
#define SELA   0x01000100u   // v_perm: dup low u16 of src into both halves
#define SELB   0x03020302u   // v_perm: dup high u16 of src into both halves

typedef short          bf16x8 __attribute__((ext_vector_type(8)));
typedef float          f32x16 __attribute__((ext_vector_type(16)));

union PkU { uint32_t u; __half h[2]; };

__device__ __forceinline__ float fexp2(float x) { return __builtin_amdgcn_exp2f(x); }
__device__ __forceinline__ float flog2(float x) { return __builtin_amdgcn_logf(x); }
__device__ __forceinline__ unsigned short f2bf(float f) {
    uint32_t u = __float_as_uint(f);
    u += 0x7FFFu + ((u >> 16) & 1u);
    return (unsigned short)(u >> 16);
}
__device__ __forceinline__ float ubf(unsigned short s) {
    return __uint_as_float((uint32_t)s << 16);
}
__device__ __forceinline__ uint32_t bfpack(float a, float b) {
    return (uint32_t)f2bf(a) | ((uint32_t)f2bf(b) << 16);
}
__device__ __forceinline__ uint32_t h1(float x) {
    return (uint32_t)__half_as_ushort(__float2half_rn(x));
}
__device__ __forceinline__ uint32_t hdup(float x) { uint32_t t = h1(x); return t | (t << 16); }
__device__ __forceinline__ uint32_t hpack(float a, float b) { return h1(a) | (h1(b) << 16); }

// packed-f16 primitives, all operands in VGPRs (r14 NaN = inline-const op_sel)
__device__ __forceinline__ uint32_t pk_fma(uint32_t a, uint32_t b, uint32_t c) {
    uint32_t d;
    asm("v_pk_fma_f16 %0, %1, %2, %3" : "=v"(d) : "v"(a), "v"(b), "v"(c));
    return d;
}
__device__ __forceinline__ uint32_t pk_nfma(uint32_t a, uint32_t b, uint32_t c) {
    uint32_t d;
    asm("v_pk_fma_f16 %0, %1, %2, %3 neg_lo:[1,0,0] neg_hi:[1,0,0]"
        : "=v"(d) : "v"(a), "v"(b), "v"(c));
    return d;
}
__device__ __forceinline__ uint32_t pk_max(uint32_t a, uint32_t b) {
    uint32_t d;
    asm("v_pk_max_f16 %0, %1, %2" : "=v"(d) : "v"(a), "v"(b));
    return d;
}
__device__ __forceinline__ uint32_t pk_addf(uint32_t a, uint32_t b) {
    uint32_t d;
    asm("v_pk_add_f16 %0, %1, %2" : "=v"(d) : "v"(a), "v"(b));
    return d;
}
__device__ __forceinline__ uint32_t pk_shl(uint32_t a, uint32_t sh) {
    uint32_t d;
    asm("v_pk_lshlrev_b16 %0, %1, %2" : "=v"(d) : "v"(sh), "v"(a));
    return d;
}
__device__ __forceinline__ uint32_t pk_addu(uint32_t a, uint32_t b) {
    uint32_t d;
    asm("v_pk_add_u16 %0, %1, %2" : "=v"(d) : "v"(a), "v"(b));
    return d;
}
__device__ __forceinline__ uint32_t perm(uint32_t src, uint32_t sel) {
    uint32_t d;
    asm("v_perm_b32 %0, %1, %2, %3" : "=v"(d) : "v"(src), "v"(src), "v"(sel));
    return d;
}

// ---------------------------------------------------------------------------
// K1. Per-(j,d) params (192 blocks).
//  smC2[j*64+d] = {s'|ms'<<16, C'dup}  (8 B — de-dup'd; expand via v_perm)
//  pqfH/L, zfH/L: bf16 hi/lo split-GEMM features; CjS; zpkT f16 i-pairs of z.
// ---------------------------------------------------------------------------
__global__ __launch_bounds__(256) void k1(
    const float* __restrict__ z, const float* __restrict__ zm,
    const float* __restrict__ zlv,
    uint2* __restrict__ smC2,
    uint32_t* __restrict__ pqfH, uint32_t* __restrict__ pqfL,
    uint32_t* __restrict__ zfH, uint32_t* __restrict__ zfL,
    float* __restrict__ CjS, uint32_t* __restrict__ zpkT)
{
    __shared__ float L[32][65];
    int tid = threadIdx.x, lane = tid & 63, row = tid >> 6;

    if (blockIdx.x < 128) {         // ---- j-side: 16 rows ----
        int jb = blockIdx.x * 16;
        #pragma unroll
        for (int c = 0; c < 4; ++c) {
            int j   = jb + c * 4 + row;
            int idx = j * DD + lane;
            float mean = zm[idx], lv = zlv[idx];
            float p   = -0.72134752f * fexp2(-lv * LOG2E);
            float q   = -2.0f * mean * p;
            float c22 = -0.72134752f * (lv + LOG2PI);
            float sp  = 5.65685424f * __builtin_sqrtf(-p);
            float msp = -mean * sp;
            float Cp  = fmaf(32.0f, c22, 1952.0f);
            smC2[idx] = make_uint2(hpack(sp, msp), hdup(Cp));
            unsigned short hp = f2bf(p), hq = f2bf(q);
            pqfH[idx] = (uint32_t)hp | ((uint32_t)hq << 16);
            pqfL[idx] = bfpack(p - ubf(hp), q - ubf(hq));
            float t = fmaf(mean * mean, p, c22);
            #pragma unroll
            for (int off = 32; off; off >>= 1) t += __shfl_xor(t, off, 64);
            if (lane == 0) CjS[j] = fmaf(t + 64.0f, 65536.0f, BIAS_F);
        }
    } else {                        // ---- i-side: 32 rows ----
        int ib = (blockIdx.x - 128) * 32;
        #pragma unroll
        for (int c = 0; c < 8; ++c) {
            int il  = c * 4 + row;
            int idx = (ib + il) * DD + lane;
            float zv = z[idx];
            L[il][lane] = zv;
            float z2 = zv * zv;
            unsigned short hz2 = f2bf(z2), hz = f2bf(zv);
            zfH[idx] = (uint32_t)hz2 | ((uint32_t)hz << 16);
            zfL[idx] = bfpack(z2 - ubf(hz2), zv - ubf(hz));
        }
        __syncthreads();
        #pragma unroll
        for (int k = 0; k < 4; ++k) {
            int e = k * 256 + tid;
            int u = e & 7, d = (e >> 3) & 63, itl = e >> 9;
            float za = L[itl * 16 + 2 * u][d];
            float zb = L[itl * 16 + 2 * u + 1][d];
            zpkT[((ib >> 4) + itl) * 512 + d * 8 + u] = hpack(za, zb);
        }
    }
}

// ---------------------------------------------------------------------------
// KW. Merged K3+K2, 512-thr blocks, grid 768.
// blocks [0,512): K3 — 8 waves; wave w owns a PRIVATE 64-j slice
//   (j0 = jsl*512 + (w&3)*64 + (w>>2)*256); f16-Schraudolph, de-dup'd 8B
//   loads + 2 v_perm expansion. Waves w and w+4 pair-merge via 8KB LDS into
//   slice jsl*4+(w-4) (128 j), f32 pair-add, stored f16 x2^-4.
// blocks [512,768): K2 — split bf16 MFMA GEMM + dual-clamped f32 Schraudolph
//   (r15/r16-validated), remapped to 8 waves/block.
// ---------------------------------------------------------------------------
__global__ __launch_bounds__(512) void kw(
    const uint2* __restrict__ smC2, const uint32_t* __restrict__ zpkT,
    const uint32_t* __restrict__ zfH, const uint32_t* __restrict__ zfL,
    const uint32_t* __restrict__ pqfH, const uint32_t* __restrict__ pqfL,
    const float* __restrict__ CjS,
    uint32_t* __restrict__ sums, float* __restrict__ k2part)
{
    __shared__ float shbuf[2048];   // 8 KB, shared by both paths
    int tid = threadIdx.x, lane = tid & 63, w = tid >> 6;

    if (blockIdx.x < 512) {
        // ================= K3 path =================
        int it = blockIdx.x >> 2, jsl = blockIdx.x & 3;
        int j0 = jsl * 512 + (w & 3) * 64 + (w >> 2) * 256;

        uint32_t zpk[8], acc[8];
        #pragma unroll
        for (int u = 0; u < 8; ++u) {
            zpk[u] = zpkT[it * 512 + lane * 8 + u];
            acc[u] = 0u;
        }
        uint32_t kk = KK16, sh5 = SHL5, clf = C1250H, sA = SELA, sB = SELB;
        asm volatile("" : "+v"(kk), "+v"(sh5), "+v"(clf), "+v"(sA), "+v"(sB));

        const uint2* sp2 = smC2 + (size_t)j0 * DD + lane;
        #pragma unroll 4
        for (int jj = 0; jj < 64; ++jj) {
            uint2 v = sp2[(size_t)jj * DD];        // {s'|ms', C'dup}
            uint32_t sd = perm(v.x, sA);           // s' dup
            uint32_t md = perm(v.x, sB);           // ms' dup
            #pragma unroll
            for (int u = 0; u < 8; ++u) {
                uint32_t wp = pk_fma(zpk[u], sd, md);   // w' = z*s' + ms'
                uint32_t y  = pk_nfma(wp, wp, v.y);     // y  = C' - w'^2
                y = pk_max(y, clf);
                uint32_t e = pk_addu(pk_shl(y, sh5), kk);
                acc[u] = pk_addf(acc[u], e);
            }
        }

        uint32_t* sl = (uint32_t*)shbuf;
        if (w < 4) {
            #pragma unroll
            for (int u = 0; u < 8; ++u) sl[(w * 8 + u) * 64 + lane] = acc[u];
        }
        __syncthreads();
        if (w >= 4) {
            int slice = jsl * 4 + (w - 4);
            #pragma unroll
            for (int u = 0; u < 8; ++u) {
                PkU a, b;
                a.u = acc[u];
                b.u = sl[((w - 4) * 8 + u) * 64 + lane];
                float lo = __half2float(a.h[0]) + __half2float(b.h[0]);
                float hi = __half2float(a.h[1]) + __half2float(b.h[1]);
                sums[((size_t)slice * 1024 + it * 8 + u) * 64 + lane] =
                    hpack(lo * 0.0625f, hi * 0.0625f);
            }
        }
    } else {
        // ================= K2 path =================
        float* cjsL = shbuf;
        for (int t = tid; t < NN; t += 512) cjsL[t] = CjS[t];
        __syncthreads();

        int gid = (blockIdx.x - 512) * 8 + w;   // 0..2047
        int it = gid >> 5, jg = gid & 31;
        int l31 = lane & 31, h = lane >> 5;

        const char* zbH = (const char*)zfH + (size_t)(it * 32 + l31) * 256 + h * 16;
        const char* zbL = (const char*)zfL + (size_t)(it * 32 + l31) * 256 + h * 16;
        bf16x8 BH[8], BL[8];
        #pragma unroll
        for (int kc = 0; kc < 8; ++kc) {
            BH[kc] = *(const bf16x8*)(zbH + kc * 32);
            BL[kc] = *(const bf16x8*)(zbL + kc * 32);
        }

        float isum = 0.0f;
        #pragma unroll
        for (int t4 = 0; t4 < 2; ++t4) {
            int jt = jg * 2 + t4;
            const char* abH = (const char*)pqfH + (size_t)(jt * 32 + l31) * 256 + h * 16;
            const char* abL = (const char*)pqfL + (size_t)(jt * 32 + l31) * 256 + h * 16;
            f32x16 acc;
            #pragma unroll
            for (int r = 0; r < 16; ++r) acc[r] = 0.0f;
            #pragma unroll
            for (int kc = 0; kc < 8; ++kc) {
                bf16x8 AH = *(const bf16x8*)(abH + kc * 32);
                bf16x8 AL = *(const bf16x8*)(abL + kc * 32);
                acc = __builtin_amdgcn_mfma_f32_32x32x16_bf16(AH, BH[kc], acc, 0, 0, 0);
                acc = __builtin_amdgcn_mfma_f32_32x32x16_bf16(AH, BL[kc], acc, 0, 0, 0);
                acc = __builtin_amdgcn_mfma_f32_32x32x16_bf16(AL, BH[kc], acc, 0, 0, 0);
            }
            #pragma unroll
            for (int r = 0; r < 16; ++r) {
                int R = (r & 3) + 8 * (r >> 2) + 4 * h;
                float y = fmaf(acc[r], 65536.0f, cjsL[jt * 32 + R]);
                y = fminf(fmaxf(y, CLAMP_LO), CLAMP_HI);
                isum += __uint_as_float((__float_as_uint(y) << 7) + KBIT);
            }
        }
        isum += __shfl_xor(isum, 32, 64);
        if (lane < 32) k2part[(size_t)jg * NN + it * 32 + l31] = isum;
    }
}

// ---------------------------------------------------------------------------
// K5. diff[i] = LN2*( sum_d log2(sum_{16} sums) - log2(sum_{32} k2part) - 128 )
//  (K3: +7/d bias and 2^-4 store scale -> +448-256 = +192; K2: +64; net 128.)
// ---------------------------------------------------------------------------
__global__ __launch_bounds__(256) void k5(
    const __half* __restrict__ sums, const float* __restrict__ k2part,
    float* __restrict__ diff)
{
    int lane = threadIdx.x & 63, w = threadIdx.x >> 6;
    int i = blockIdx.x * 4 + w;
    int ip = i >> 1, hsel = i & 1;

    float tot = 0.0f;
    #pragma unroll
    for (int q = 0; q < 16; ++q)
        tot += __half2float(sums[(((size_t)q * 1024 + ip) * 64 + lane) * 2 + hsel]);
    float t = flog2(tot);
    #pragma unroll
    for (int off = 32; off; off >>= 1) t += __shfl_xor(t, off, 64);

    float s2 = (lane < 32) ? k2part[(size_t)lane * NN + i] : 0.0f;
    #pragma unroll
    for (int off = 32; off; off >>= 1) s2 += __shfl_xor(s2, off, 64);

    if (lane == 0) diff[i] = LN2 * (t - flog2(s2) - 128.0f);
}

// ---------------------------------------------------------------------------
// K6: out = mean_i diff[i]
// ---------------------------------------------------------------------------
__global__ __launch_bounds__(256) void k6(
    const float* __restrict__ diff, float* __restrict__ out)
{
    __shared__ float red[256];
    int tid = threadIdx.x;
    float t = 0.0f;
    for (int k = tid; k < NN; k += 256) t += diff[k];
    red[tid] = t;
    __syncthreads();
    #pragma unroll
    for (int off = 128; off; off >>= 1) {
        if (tid < off) red[tid] += red[tid + off];
        __syncthreads();
    }
    if (tid == 0) out[0] = red[0] * (1.0f / (float)NN);
}

extern "C" void kernel_launch(void* const* d_in, const int* in_sizes, int n_in,
                              void* d_out, int out_size, void* d_ws, size_t ws_size,
                              hipStream_t stream)
{
    const float* z   = (const float*)d_in[0];
    const float* zm  = (const float*)d_in[1];
    const float* zlv = (const float*)d_in[2];
    float* out = (float*)d_out;

    char* b = (char*)d_ws;
    uint2*    smC2 = (uint2*)(b);                               // 1 MB
    uint32_t* pqfH = (uint32_t*)(b + (1 << 20));                // 512 KB
    uint32_t* pqfL = (uint32_t*)(b + (1 << 20) + (512 << 10));  // 512 KB
    uint32_t* zfH  = (uint32_t*)(b + (2 << 20));                // 512 KB
    uint32_t* zfL  = (uint32_t*)(b + (2 << 20) + (512 << 10));  // 512 KB
    uint32_t* zpkT = (uint32_t*)(b + (3 << 20));                // 256 KB
    float*    CjS  = (float*)(b + (3 << 20) + (256 << 10));     // 8 KB
    uint32_t* sums = (uint32_t*)(b + (3 << 20) + (512 << 10));  // 4 MB
    float*    k2p  = (float*)(b + (7 << 20) + (512 << 10));     // 256 KB
    float*    diff = (float*)(b + (7 << 20) + (768 << 10));     // 8 KB

    k1<<<192, 256, 0, stream>>>(z, zm, zlv, smC2, pqfH, pqfL, zfH, zfL, CjS, zpkT);
    kw<<<768, 512, 0, stream>>>(smC2, zpkT, zfH, zfL, pqfH, pqfL, CjS, sums, k2p);
    k5<<<512, 256, 0, stream>>>((const __half*)sums, k2p, diff);
    k6<<<1,   256, 0, stream>>>(diff, out);
}

// Round 18
// 49.028 us; speedup vs baseline: 1.0546x; 1.0546x over previous
//
#include <hip/hip_runtime.h>
#include <hip/hip_fp16.h>
#include <math.h>
#include <stdint.h>

#define LOG2E  1.44269504088896340736f
#define LN2    0.69314718055994530942f
#define LOG2PI 1.8378770664093453f

#define NN 2048
#define DD 64

// f32 Schraudolph (validated r8-r17): scale 2^16, window [2^23,2^24)
#define BIAS_F   16252928.0f
#define KBIT     2205910303u
#define CLAMP_LO 8388608.0f
#define CLAMP_HI 16777215.0f

// f16 Schraudolph (validated r15-r17): y = 32*(arg+7)+1728 in [1250,2048)
#define C1250H 0x64E264E2u
#define KK16   0x63DC63DCu
#define SHL5   0x00050005u
#define SELA   0x01000100u   // v_perm: dup low u16 into both halves
#define SELB   0x03020302u   // v_perm: dup high u16 into both halves

typedef short          bf16x8 __attribute__((ext_vector_type(8)));
typedef float          f32x16 __attribute__((ext_vector_type(16)));

union PkU { uint32_t u; __half h[2]; };

__device__ __forceinline__ float fexp2(float x) { return __builtin_amdgcn_exp2f(x); }
__device__ __forceinline__ float flog2(float x) { return __builtin_amdgcn_logf(x); }
__device__ __forceinline__ unsigned short f2bf(float f) {
    uint32_t u = __float_as_uint(f);
    u += 0x7FFFu + ((u >> 16) & 1u);
    return (unsigned short)(u >> 16);
}
__device__ __forceinline__ float ubf(unsigned short s) {
    return __uint_as_float((uint32_t)s << 16);
}
__device__ __forceinline__ uint32_t bfpack(float a, float b) {
    return (uint32_t)f2bf(a) | ((uint32_t)f2bf(b) << 16);
}
__device__ __forceinline__ uint32_t h1(float x) {
    return (uint32_t)__half_as_ushort(__float2half_rn(x));
}
__device__ __forceinline__ uint32_t hdup(float x) { uint32_t t = h1(x); return t | (t << 16); }
__device__ __forceinline__ uint32_t hpack(float a, float b) { return h1(a) | (h1(b) << 16); }

// packed-f16 primitives, all operands in VGPRs (r14 NaN = inline-const op_sel)
__device__ __forceinline__ uint32_t pk_fma(uint32_t a, uint32_t b, uint32_t c) {
    uint32_t d;
    asm("v_pk_fma_f16 %0, %1, %2, %3" : "=v"(d) : "v"(a), "v"(b), "v"(c));
    return d;
}
__device__ __forceinline__ uint32_t pk_nfma(uint32_t a, uint32_t b, uint32_t c) {
    uint32_t d;
    asm("v_pk_fma_f16 %0, %1, %2, %3 neg_lo:[1,0,0] neg_hi:[1,0,0]"
        : "=v"(d) : "v"(a), "v"(b), "v"(c));
    return d;
}
__device__ __forceinline__ uint32_t pk_max(uint32_t a, uint32_t b) {
    uint32_t d;
    asm("v_pk_max_f16 %0, %1, %2" : "=v"(d) : "v"(a), "v"(b));
    return d;
}
__device__ __forceinline__ uint32_t pk_addf(uint32_t a, uint32_t b) {
    uint32_t d;
    asm("v_pk_add_f16 %0, %1, %2" : "=v"(d) : "v"(a), "v"(b));
    return d;
}
__device__ __forceinline__ uint32_t pk_shl(uint32_t a, uint32_t sh) {
    uint32_t d;
    asm("v_pk_lshlrev_b16 %0, %1, %2" : "=v"(d) : "v"(sh), "v"(a));
    return d;
}
__device__ __forceinline__ uint32_t pk_addu(uint32_t a, uint32_t b) {
    uint32_t d;
    asm("v_pk_add_u16 %0, %1, %2" : "=v"(d) : "v"(a), "v"(b));
    return d;
}
__device__ __forceinline__ uint32_t perm(uint32_t src, uint32_t sel) {
    uint32_t d;
    asm("v_perm_b32 %0, %1, %2, %3" : "=v"(d) : "v"(src), "v"(src), "v"(sel));
    return d;
}

// ---------------------------------------------------------------------------
// K1. Per-(j,d) params (192 blocks). Verbatim r17.
//  smC2[j*64+d] = {s'|ms'<<16, C'dup}  (8 B de-dup'd; expand via v_perm)
//  pqfH/L, zfH/L: bf16 hi/lo split-GEMM features; CjS; zpkT f16 i-pairs of z.
// ---------------------------------------------------------------------------
__global__ __launch_bounds__(256) void k1(
    const float* __restrict__ z, const float* __restrict__ zm,
    const float* __restrict__ zlv,
    uint2* __restrict__ smC2,
    uint32_t* __restrict__ pqfH, uint32_t* __restrict__ pqfL,
    uint32_t* __restrict__ zfH, uint32_t* __restrict__ zfL,
    float* __restrict__ CjS, uint32_t* __restrict__ zpkT)
{
    __shared__ float L[32][65];
    int tid = threadIdx.x, lane = tid & 63, row = tid >> 6;

    if (blockIdx.x < 128) {         // ---- j-side: 16 rows ----
        int jb = blockIdx.x * 16;
        #pragma unroll
        for (int c = 0; c < 4; ++c) {
            int j   = jb + c * 4 + row;
            int idx = j * DD + lane;
            float mean = zm[idx], lv = zlv[idx];
            float p   = -0.72134752f * fexp2(-lv * LOG2E);
            float q   = -2.0f * mean * p;
            float c22 = -0.72134752f * (lv + LOG2PI);
            float sp  = 5.65685424f * __builtin_sqrtf(-p);
            float msp = -mean * sp;
            float Cp  = fmaf(32.0f, c22, 1952.0f);
            smC2[idx] = make_uint2(hpack(sp, msp), hdup(Cp));
            unsigned short hp = f2bf(p), hq = f2bf(q);
            pqfH[idx] = (uint32_t)hp | ((uint32_t)hq << 16);
            pqfL[idx] = bfpack(p - ubf(hp), q - ubf(hq));
            float t = fmaf(mean * mean, p, c22);
            #pragma unroll
            for (int off = 32; off; off >>= 1) t += __shfl_xor(t, off, 64);
            if (lane == 0) CjS[j] = fmaf(t + 64.0f, 65536.0f, BIAS_F);
        }
    } else {                        // ---- i-side: 32 rows ----
        int ib = (blockIdx.x - 128) * 32;
        #pragma unroll
        for (int c = 0; c < 8; ++c) {
            int il  = c * 4 + row;
            int idx = (ib + il) * DD + lane;
            float zv = z[idx];
            L[il][lane] = zv;
            float z2 = zv * zv;
            unsigned short hz2 = f2bf(z2), hz = f2bf(zv);
            zfH[idx] = (uint32_t)hz2 | ((uint32_t)hz << 16);
            zfL[idx] = bfpack(z2 - ubf(hz2), zv - ubf(hz));
        }
        __syncthreads();
        #pragma unroll
        for (int k = 0; k < 4; ++k) {
            int e = k * 256 + tid;
            int u = e & 7, d = (e >> 3) & 63, itl = e >> 9;
            float za = L[itl * 16 + 2 * u][d];
            float zb = L[itl * 16 + 2 * u + 1][d];
            zpkT[((ib >> 4) + itl) * 512 + d * 8 + u] = hpack(za, zb);
        }
    }
}

// ---------------------------------------------------------------------------
// KW. Merged K3+K2, 256-thr blocks, grid 1536.
// blocks [0,1024): K3 — 4 waves; block = 32-i tile x 128-j slice; wave w owns
//   a PRIVATE 32-j sub-slice and ALL 16 i-pairs (ILP experiment: 80 pk-insts
//   with 16 independent chains per 8B load). 4-wave f32 merge via 16KB LDS.
// blocks [1024,1536): K2 — split bf16 MFMA GEMM + dual-clamped f32
//   Schraudolph (validated r15-r17), gid = (blk-1024)*4 + w.
// ---------------------------------------------------------------------------
__global__ __launch_bounds__(256) void kw(
    const uint2* __restrict__ smC2, const uint32_t* __restrict__ zpkT,
    const uint32_t* __restrict__ zfH, const uint32_t* __restrict__ zfL,
    const uint32_t* __restrict__ pqfH, const uint32_t* __restrict__ pqfL,
    const float* __restrict__ CjS,
    uint32_t* __restrict__ sums, float* __restrict__ k2part)
{
    __shared__ uint32_t shbuf[4096];   // 16 KB, shared by both paths
    int tid = threadIdx.x, lane = tid & 63, w = tid >> 6;

    if (blockIdx.x < 1024) {
        // ================= K3 path =================
        int it = blockIdx.x >> 4, jb = blockIdx.x & 15;
        int j0 = jb * 128 + w * 32;

        uint32_t zpk[16], acc[16];
        #pragma unroll
        for (int u = 0; u < 16; ++u) {
            zpk[u] = zpkT[(2 * it + (u >> 3)) * 512 + lane * 8 + (u & 7)];
            acc[u] = 0u;
        }
        uint32_t kk = KK16, sh5 = SHL5, clf = C1250H, sA = SELA, sB = SELB;
        asm volatile("" : "+v"(kk), "+v"(sh5), "+v"(clf), "+v"(sA), "+v"(sB));

        const uint2* sp2 = smC2 + (size_t)j0 * DD + lane;
        #pragma unroll 2
        for (int jj = 0; jj < 32; ++jj) {
            uint2 v = sp2[(size_t)jj * DD];        // {s'|ms', C'dup}
            uint32_t sd = perm(v.x, sA);           // s' dup
            uint32_t md = perm(v.x, sB);           // ms' dup
            #pragma unroll
            for (int u = 0; u < 16; ++u) {
                uint32_t wp = pk_fma(zpk[u], sd, md);   // w' = z*s' + ms'
                uint32_t y  = pk_nfma(wp, wp, v.y);     // y  = C' - w'^2
                y = pk_max(y, clf);
                uint32_t e = pk_addu(pk_shl(y, sh5), kk);
                acc[u] = pk_addf(acc[u], e);
            }
        }

        #pragma unroll
        for (int u = 0; u < 16; ++u) shbuf[(w * 16 + u) * 64 + lane] = acc[u];
        __syncthreads();
        #pragma unroll
        for (int k = 0; k < 4; ++k) {
            int e = k * 256 + tid;      // 1024 entries: u = e>>6, d = e&63
            int u = e >> 6, d = e & 63;
            float lo = 0.0f, hi = 0.0f;
            #pragma unroll
            for (int w2 = 0; w2 < 4; ++w2) {
                PkU a; a.u = shbuf[(w2 * 16 + u) * 64 + d];
                lo += __half2float(a.h[0]);
                hi += __half2float(a.h[1]);
            }
            sums[((size_t)jb * 1024 + it * 16 + u) * 64 + d] =
                hpack(lo * 0.0625f, hi * 0.0625f);
        }
    } else {
        // ================= K2 path =================
        float* cjsL = (float*)shbuf;
        for (int t = tid; t < NN; t += 256) cjsL[t] = CjS[t];
        __syncthreads();

        int gid = (blockIdx.x - 1024) * 4 + w;   // 0..2047
        int it = gid >> 5, jg = gid & 31;
        int l31 = lane & 31, h = lane >> 5;

        const char* zbH = (const char*)zfH + (size_t)(it * 32 + l31) * 256 + h * 16;
        const char* zbL = (const char*)zfL + (size_t)(it * 32 + l31) * 256 + h * 16;
        bf16x8 BH[8], BL[8];
        #pragma unroll
        for (int kc = 0; kc < 8; ++kc) {
            BH[kc] = *(const bf16x8*)(zbH + kc * 32);
            BL[kc] = *(const bf16x8*)(zbL + kc * 32);
        }

        float isum = 0.0f;
        #pragma unroll
        for (int t4 = 0; t4 < 2; ++t4) {
            int jt = jg * 2 + t4;
            const char* abH = (const char*)pqfH + (size_t)(jt * 32 + l31) * 256 + h * 16;
            const char* abL = (const char*)pqfL + (size_t)(jt * 32 + l31) * 256 + h * 16;
            f32x16 acc;
            #pragma unroll
            for (int r = 0; r < 16; ++r) acc[r] = 0.0f;
            #pragma unroll
            for (int kc = 0; kc < 8; ++kc) {
                bf16x8 AH = *(const bf16x8*)(abH + kc * 32);
                bf16x8 AL = *(const bf16x8*)(abL + kc * 32);
                acc = __builtin_amdgcn_mfma_f32_32x32x16_bf16(AH, BH[kc], acc, 0, 0, 0);
                acc = __builtin_amdgcn_mfma_f32_32x32x16_bf16(AH, BL[kc], acc, 0, 0, 0);
                acc = __builtin_amdgcn_mfma_f32_32x32x16_bf16(AL, BH[kc], acc, 0, 0, 0);
            }
            #pragma unroll
            for (int r = 0; r < 16; ++r) {
                int R = (r & 3) + 8 * (r >> 2) + 4 * h;
                float y = fmaf(acc[r], 65536.0f, cjsL[jt * 32 + R]);
                y = fminf(fmaxf(y, CLAMP_LO), CLAMP_HI);
                isum += __uint_as_float((__float_as_uint(y) << 7) + KBIT);
            }
        }
        isum += __shfl_xor(isum, 32, 64);
        if (lane < 32) k2part[(size_t)jg * NN + it * 32 + l31] = isum;
    }
}

// ---------------------------------------------------------------------------
// K5. diff[i] = LN2*( sum_d log2(sum_{16} sums) - log2(sum_{32} k2part) - 128 )
//  (K3: +7/d bias, 2^-4 store scale -> +448-256 = +192; K2: +64; net 128.)
// ---------------------------------------------------------------------------
__global__ __launch_bounds__(256) void k5(
    const __half* __restrict__ sums, const float* __restrict__ k2part,
    float* __restrict__ diff)
{
    int lane = threadIdx.x & 63, w = threadIdx.x >> 6;
    int i = blockIdx.x * 4 + w;
    int ip = i >> 1, hsel = i & 1;

    float tot = 0.0f;
    #pragma unroll
    for (int q = 0; q < 16; ++q)
        tot += __half2float(sums[(((size_t)q * 1024 + ip) * 64 + lane) * 2 + hsel]);
    float t = flog2(tot);
    #pragma unroll
    for (int off = 32; off; off >>= 1) t += __shfl_xor(t, off, 64);

    float s2 = (lane < 32) ? k2part[(size_t)lane * NN + i] : 0.0f;
    #pragma unroll
    for (int off = 32; off; off >>= 1) s2 += __shfl_xor(s2, off, 64);

    if (lane == 0) diff[i] = LN2 * (t - flog2(s2) - 128.0f);
}

// ---------------------------------------------------------------------------
// K6: out = mean_i diff[i]
// ---------------------------------------------------------------------------
__global__ __launch_bounds__(256) void k6(
    const float* __restrict__ diff, float* __restrict__ out)
{
    __shared__ float red[256];
    int tid = threadIdx.x;
    float t = 0.0f;
    for (int k = tid; k < NN; k += 256) t += diff[k];
    red[tid] = t;
    __syncthreads();
    #pragma unroll
    for (int off = 128; off; off >>= 1) {
        if (tid < off) red[tid] += red[tid + off];
        __syncthreads();
    }
    if (tid == 0) out[0] = red[0] * (1.0f / (float)NN);
}

extern "C" void kernel_launch(void* const* d_in, const int* in_sizes, int n_in,
                              void* d_out, int out_size, void* d_ws, size_t ws_size,
                              hipStream_t stream)
{
    const float* z   = (const float*)d_in[0];
    const float* zm  = (const float*)d_in[1];
    const float* zlv = (const float*)d_in[2];
    float* out = (float*)d_out;

    char* b = (char*)d_ws;
    uint2*    smC2 = (uint2*)(b);                               // 1 MB
    uint32_t* pqfH = (uint32_t*)(b + (1 << 20));                // 512 KB
    uint32_t* pqfL = (uint32_t*)(b + (1 << 20) + (512 << 10));  // 512 KB
    uint32_t* zfH  = (uint32_t*)(b + (2 << 20));                // 512 KB
    uint32_t* zfL  = (uint32_t*)(b + (2 << 20) + (512 << 10));  // 512 KB
    uint32_t* zpkT = (uint32_t*)(b + (3 << 20));                // 256 KB
    float*    CjS  = (float*)(b + (3 << 20) + (256 << 10));     // 8 KB
    uint32_t* sums = (uint32_t*)(b + (3 << 20) + (512 << 10));  // 4 MB
    float*    k2p  = (float*)(b + (7 << 20) + (512 << 10));     // 256 KB
    float*    diff = (float*)(b + (7 << 20) + (768 << 10));     // 8 KB

    k1<<<192,  256, 0, stream>>>(z, zm, zlv, smC2, pqfH, pqfL, zfH, zfL, CjS, zpkT);
    kw<<<1536, 256, 0, stream>>>(smC2, zpkT, zfH, zfL, pqfH, pqfL, CjS, sums, k2p);
    k5<<<512,  256, 0, stream>>>((const __half*)sums, k2p, diff);
    k6<<<1,    256, 0, stream>>>(diff, out);
}